// Round 5
// baseline (6009.335 us; speedup 1.0000x reference)
//
#include <hip/hip_runtime.h>

#define N_A   50000
#define N_B   50000
#define NE    1600000
#define HID   128
#define DOUT  64

// Bucketing: 64 dst-nodes per bucket
#define BSH    6
#define BNODES 64
#define NBKT   782            // ceil(50000 / 64)
#define ACH    16384          // edges per scatter workgroup

// ---------------------------------------------------------------------------
// Bucket histogram: LDS hist per WG, flush with global atomics.
// ---------------------------------------------------------------------------
__global__ __launch_bounds__(256)
void bucket_hist(const int* __restrict__ dst, int* __restrict__ cnt, int n) {
    __shared__ int h[NBKT];
    for (int i = threadIdx.x; i < NBKT; i += 256) h[i] = 0;
    __syncthreads();
    for (int i = blockIdx.x * 256 + threadIdx.x; i < n; i += gridDim.x * 256)
        atomicAdd(&h[dst[i] >> BSH], 1);
    __syncthreads();
    for (int i = threadIdx.x; i < NBKT; i += 256)
        if (h[i]) atomicAdd(&cnt[i], h[i]);
}

// ---------------------------------------------------------------------------
// Exclusive scan of bucket counts (one block per graph; NBKT < 1024).
// Writes base[NBKT] = etot sentinel and initializes global cursors.
// ---------------------------------------------------------------------------
__global__ __launch_bounds__(1024)
void bucket_scan(const int* __restrict__ cnt, int* __restrict__ base,
                 int* __restrict__ gcur, int etot) {
    __shared__ int s[1024];
    const int g = blockIdx.x;
    cnt  += g * NBKT;
    base += g * (NBKT + 1);
    gcur += g * NBKT;
    int t = threadIdx.x;
    int v = (t < NBKT) ? cnt[t] : 0;
    s[t] = v;
    __syncthreads();
    for (int off = 1; off < 1024; off <<= 1) {
        int x = (t >= off) ? s[t - off] : 0;
        __syncthreads();
        s[t] += x;
        __syncthreads();
    }
    if (t < NBKT) { int b = s[t] - v; base[t] = b; gcur[t] = b; }
    if (t == NBKT) base[t] = etot;
}

// ---------------------------------------------------------------------------
// Bucketed scatter: each WG takes ACH contiguous edges, histograms them in
// LDS, reserves per-bucket ranges with ONE global atomic per non-empty
// bucket, then writes packed edges (dst_local<<16 | src) in contiguous
// per-bucket runs (~170B avg) -> near-full-line write traffic.
// ---------------------------------------------------------------------------
__global__ __launch_bounds__(256)
void bucket_scatter(const int* __restrict__ src, const int* __restrict__ dst,
                    int* __restrict__ gcur, unsigned int* __restrict__ ebuf, int n) {
    __shared__ int hist[NBKT];
    __shared__ int lbase[NBKT];
    for (int i = threadIdx.x; i < NBKT; i += 256) hist[i] = 0;
    __syncthreads();
    const int c0 = blockIdx.x * ACH;
    const int c1 = min(c0 + ACH, n);
    for (int i = c0 + threadIdx.x; i < c1; i += 256)
        atomicAdd(&hist[dst[i] >> BSH], 1);
    __syncthreads();
    for (int i = threadIdx.x; i < NBKT; i += 256) {
        int h = hist[i];
        lbase[i] = h ? atomicAdd(&gcur[i], h) : 0;
    }
    __syncthreads();
    for (int i = threadIdx.x; i < NBKT; i += 256) hist[i] = 0;  // reuse as cursor
    __syncthreads();
    for (int i = c0 + threadIdx.x; i < c1; i += 256) {
        int d = dst[i], sv = src[i];
        int b = d >> BSH;
        int p = lbase[b] + atomicAdd(&hist[b], 1);
        ebuf[p] = ((unsigned)(d & (BNODES - 1)) << 16) | (unsigned)sv;
    }
}

// ---------------------------------------------------------------------------
// Fused bucketed mean-aggregation: one WG per bucket. 64-node x 128-feat
// fp32 accumulator in LDS (32KB -> 4 WG/CU). Per edge: wave gathers the
// 512B source row (float2/lane) and LDS-atomicAdds into the dst row; degree
// counted in LDS; coalesced mean writes at the end.
// ---------------------------------------------------------------------------
__global__ __launch_bounds__(256)
void bucket_agg(const float* __restrict__ h, const unsigned int* __restrict__ ebuf,
                const int* __restrict__ base, float* __restrict__ outm, int nnodes) {
    __shared__ float acc[BNODES * 128];
    __shared__ int deg[BNODES];
    const int t = threadIdx.x;
    const int w = t >> 6, l = t & 63;
    for (int i = t; i < BNODES * 128; i += 256) acc[i] = 0.f;
    if (t < BNODES) deg[t] = 0;
    __syncthreads();

    const int b = blockIdx.x;
    const int e0 = base[b], e1 = base[b + 1];
    const int cnt = e1 - e0;
    const float2* __restrict__ h2 = (const float2*)h;

    // contiguous stripe per wave
    int ws = e0 + (cnt * w) / 4;
    int we = e0 + (cnt * (w + 1)) / 4;
    int i = ws;
    for (; i + 4 <= we; i += 4) {       // 4 gathers in flight
        unsigned p0 = ebuf[i], p1 = ebuf[i + 1], p2 = ebuf[i + 2], p3 = ebuf[i + 3];
        float2 x0 = h2[(p0 & 0xffff) * 64 + l];
        float2 x1 = h2[(p1 & 0xffff) * 64 + l];
        float2 x2 = h2[(p2 & 0xffff) * 64 + l];
        float2 x3 = h2[(p3 & 0xffff) * 64 + l];
        int d0 = p0 >> 16, d1 = p1 >> 16, d2 = p2 >> 16, d3 = p3 >> 16;
        if (l == 0) {
            atomicAdd(&deg[d0], 1); atomicAdd(&deg[d1], 1);
            atomicAdd(&deg[d2], 1); atomicAdd(&deg[d3], 1);
        }
        atomicAdd(&acc[d0 * 128 + 2 * l], x0.x); atomicAdd(&acc[d0 * 128 + 2 * l + 1], x0.y);
        atomicAdd(&acc[d1 * 128 + 2 * l], x1.x); atomicAdd(&acc[d1 * 128 + 2 * l + 1], x1.y);
        atomicAdd(&acc[d2 * 128 + 2 * l], x2.x); atomicAdd(&acc[d2 * 128 + 2 * l + 1], x2.y);
        atomicAdd(&acc[d3 * 128 + 2 * l], x3.x); atomicAdd(&acc[d3 * 128 + 2 * l + 1], x3.y);
    }
    for (; i < we; ++i) {
        unsigned pe = ebuf[i];
        int dl = pe >> 16;
        float2 x = h2[(pe & 0xffff) * 64 + l];
        if (l == 0) atomicAdd(&deg[dl], 1);
        atomicAdd(&acc[dl * 128 + 2 * l], x.x);
        atomicAdd(&acc[dl * 128 + 2 * l + 1], x.y);
    }
    __syncthreads();

    const int nd0 = b << BSH;
    for (int j = w; j < BNODES; j += 4) {
        int nd = nd0 + j;
        if (nd >= nnodes) break;
        float inv = 1.f / fmaxf((float)deg[j], 1.f);
        float2 v;
        v.x = acc[j * 128 + 2 * l] * inv;
        v.y = acc[j * 128 + 2 * l + 1] * inv;
        ((float2*)outm)[nd * 64 + l] = v;
    }
}

// ---------------------------------------------------------------------------
// Row-tiled fp32 GEMM: out[r][c] = act( A@W1 (+ B@W2) + bias )  (unchanged)
// 256 threads, 64-row tile, 4 rows/thread, W staged in 64-col LDS chunks.
// Safe for out == A (block reads/writes only its own 64 rows).
// ---------------------------------------------------------------------------
#define AS 132   // Asm leading-dim stride (floats)

__device__ __forceinline__ void fma4(float4& a, float s, const float4& w) {
    a.x += s * w.x; a.y += s * w.y; a.z += s * w.z; a.w += s * w.w;
}

template <int COLS, bool TWO, bool RELU>
__global__ __launch_bounds__(256)
void gemm_rt(const float* __restrict__ A, const float* __restrict__ B,
             const float* __restrict__ W1, const float* __restrict__ W2,
             const float* __restrict__ bias, float* __restrict__ out, int nrows) {
    constexpr int NCH = COLS / 64;
    __shared__ float Asm[64 * AS];
    __shared__ float Wsm[128 * 64];
    const int t = threadIdx.x;
    const int p = t >> 4, m = t & 15, m4 = m * 4;
    const int r0 = 4 * p;
    const int rbase = blockIdx.x * 64;

    float4 acc[NCH][4];
#pragma unroll
    for (int c = 0; c < NCH; ++c)
#pragma unroll
        for (int i = 0; i < 4; ++i)
            acc[c][i] = make_float4(0.f, 0.f, 0.f, 0.f);

#pragma unroll
    for (int sidx = 0; sidx < (TWO ? 2 : 1); ++sidx) {
        const float* Asrc = (TWO && sidx) ? B : A;
        const float* Wsrc = (TWO && sidx) ? W2 : W1;
        __syncthreads();
        {   // stage 64x128 A tile as 2048 float4
            const float4* g = (const float4*)Asrc;
#pragma unroll
            for (int it = 0; it < 8; ++it) {
                int f = t + 256 * it;
                int r = f >> 5, c = f & 31;
                int gr = rbase + r;
                float4 v = make_float4(0.f, 0.f, 0.f, 0.f);
                if (gr < nrows) v = g[(size_t)gr * 32 + c];
                *(float4*)&Asm[r * AS + 4 * c] = v;
            }
        }
#pragma unroll
        for (int ch = 0; ch < NCH; ++ch) {
            if (ch > 0) __syncthreads();
            {   // stage 128x64 W chunk
                const float4* gw = (const float4*)Wsrc;
#pragma unroll
                for (int it = 0; it < 8; ++it) {
                    int f = t + 256 * it;
                    int k = f >> 4, c4 = f & 15;
                    float4 v = gw[k * (COLS / 4) + ch * 16 + c4];
                    *(float4*)&Wsm[k * 64 + 4 * c4] = v;
                }
            }
            __syncthreads();
#pragma unroll 2
            for (int k = 0; k < 128; k += 4) {
                float4 w0 = *(const float4*)&Wsm[(k + 0) * 64 + m4];
                float4 w1 = *(const float4*)&Wsm[(k + 1) * 64 + m4];
                float4 w2 = *(const float4*)&Wsm[(k + 2) * 64 + m4];
                float4 w3 = *(const float4*)&Wsm[(k + 3) * 64 + m4];
#pragma unroll
                for (int i = 0; i < 4; ++i) {
                    float4 a = *(const float4*)&Asm[(r0 + i) * AS + k];
                    fma4(acc[ch][i], a.x, w0);
                    fma4(acc[ch][i], a.y, w1);
                    fma4(acc[ch][i], a.z, w2);
                    fma4(acc[ch][i], a.w, w3);
                }
            }
        }
    }

#pragma unroll
    for (int ch = 0; ch < NCH; ++ch) {
        float4 b4 = *(const float4*)&bias[ch * 64 + m4];
#pragma unroll
        for (int i = 0; i < 4; ++i) {
            int r = rbase + r0 + i;
            if (r < nrows) {
                float4 v = acc[ch][i];
                v.x += b4.x; v.y += b4.y; v.z += b4.z; v.w += b4.w;
                if (RELU) {
                    v.x = fmaxf(v.x, 0.f); v.y = fmaxf(v.y, 0.f);
                    v.z = fmaxf(v.z, 0.f); v.w = fmaxf(v.w, 0.f);
                }
                *(float4*)&out[(size_t)r * COLS + ch * 64 + m4] = v;
            }
        }
    }
}

// ---------------------------------------------------------------------------
extern "C" void kernel_launch(void* const* d_in, const int* in_sizes, int n_in,
                              void* d_out, int out_size, void* d_ws, size_t ws_size,
                              hipStream_t stream) {
    const float* x_a   = (const float*)d_in[0];
    const float* x_b   = (const float*)d_in[1];
    const int*   ei_ab = (const int*)d_in[2];   // [2][E]: row0 src(a), row1 dst(b)
    const int*   ei_ba = (const int*)d_in[3];
    const float* Wa_in = (const float*)d_in[4];
    const float* ba_in = (const float*)d_in[5];
    const float* Wb_in = (const float*)d_in[6];
    const float* bb_in = (const float*)d_in[7];
    const float* Wl_ab = (const float*)d_in[8];   // [2][128][128]
    const float* Wr_ab = (const float*)d_in[9];
    const float* bl_ab = (const float*)d_in[10];  // [2][128]
    const float* Wl_ba = (const float*)d_in[11];
    const float* Wr_ba = (const float*)d_in[12];
    const float* bl_ba = (const float*)d_in[13];
    const float* W_out = (const float*)d_in[14];  // [128][64]
    const float* b_out = (const float*)d_in[15];
    float* out = (float*)d_out;

    // ---- workspace partition (256B aligned) ----
    char* w = (char*)d_ws;
    auto alloc = [&](size_t bytes) -> void* {
        void* pp = (void*)w;
        w += (bytes + 255) & ~(size_t)255;
        return pp;
    };
    float* hA0 = (float*)alloc((size_t)N_A * HID * 4);
    float* hA1 = (float*)alloc((size_t)N_A * HID * 4);
    float* hB0 = (float*)alloc((size_t)N_B * HID * 4);
    float* hB1 = (float*)alloc((size_t)N_B * HID * 4);
    unsigned int* ebuf_ab = (unsigned int*)alloc((size_t)NE * 4);
    unsigned int* ebuf_ba = (unsigned int*)alloc((size_t)NE * 4);
    int* cnt  = (int*)alloc((size_t)2 * NBKT * 4);        // [2][NBKT]
    int* base = (int*)alloc((size_t)2 * (NBKT + 1) * 4);  // [2][NBKT+1]
    int* gcur = (int*)alloc((size_t)2 * NBKT * 4);        // [2][NBKT]

    // ---- bucketed edge build (replaces CSR entirely) ----
    hipMemsetAsync(cnt, 0, (size_t)2 * NBKT * 4, stream);
    bucket_hist<<<256, 256, 0, stream>>>(ei_ab + NE, cnt, NE);
    bucket_hist<<<256, 256, 0, stream>>>(ei_ba + NE, cnt + NBKT, NE);
    bucket_scan<<<2, 1024, 0, stream>>>(cnt, base, gcur, NE);
    const int scat_blocks = (NE + ACH - 1) / ACH;
    bucket_scatter<<<scat_blocks, 256, 0, stream>>>(ei_ab, ei_ab + NE, gcur, ebuf_ab, NE);
    bucket_scatter<<<scat_blocks, 256, 0, stream>>>(ei_ba, ei_ba + NE, gcur + NBKT, ebuf_ba, NE);
    const int* base_ab = base;
    const int* base_ba = base + (NBKT + 1);

    const int gemm_blocks_a = (N_A + 63) / 64;
    const int gemm_blocks_b = (N_B + 63) / 64;

    // ---- input projections ----
    gemm_rt<128, false, true><<<gemm_blocks_a, 256, 0, stream>>>(
        x_a, nullptr, Wa_in, nullptr, ba_in, hA0, N_A);
    gemm_rt<128, false, true><<<gemm_blocks_b, 256, 0, stream>>>(
        x_b, nullptr, Wb_in, nullptr, bb_in, hB0, N_B);

    // ---- 2 hetero layers ----
    float* ha = hA0; float* ha_alt = hA1;
    float* hb = hB0; float* hb_alt = hB1;
    for (int l = 0; l < 2; ++l) {
        const float* wl_ab = Wl_ab + (size_t)l * HID * HID;
        const float* wr_ab = Wr_ab + (size_t)l * HID * HID;
        const float* bias_ab = bl_ab + (size_t)l * HID;
        const float* wl_ba = Wl_ba + (size_t)l * HID * HID;
        const float* wr_ba = Wr_ba + (size_t)l * HID * HID;
        const float* bias_ba = bl_ba + (size_t)l * HID;

        // mean_b <- mean of h_a over a->b ; mean_a <- mean of h_b over b->a
        bucket_agg<<<NBKT, 256, 0, stream>>>(ha, ebuf_ab, base_ab, hb_alt, N_B);
        bucket_agg<<<NBKT, 256, 0, stream>>>(hb, ebuf_ba, base_ba, ha_alt, N_A);
        // h_b' = relu(mean_b@Wl_ab + bl_ab + h_b@Wr_ab)
        gemm_rt<128, true, true><<<gemm_blocks_b, 256, 0, stream>>>(
            hb_alt, hb, wl_ab, wr_ab, bias_ab, hb_alt, N_B);
        // h_a' = relu(mean_a@Wl_ba + bl_ba + h_a@Wr_ba)
        gemm_rt<128, true, true><<<gemm_blocks_a, 256, 0, stream>>>(
            ha_alt, ha, wl_ba, wr_ba, bias_ba, ha_alt, N_A);

        float* tmp;
        tmp = ha; ha = ha_alt; ha_alt = tmp;
        tmp = hb; hb = hb_alt; hb_alt = tmp;
    }

    // ---- output projection (no relu) ----
    gemm_rt<64, false, false><<<gemm_blocks_a, 256, 0, stream>>>(
        ha, nullptr, W_out, nullptr, b_out, out, N_A);
}

// Round 6
// 1012.435 us; speedup vs baseline: 5.9355x; 5.9355x over previous
//
#include <hip/hip_runtime.h>

#define N_A   50000
#define N_B   50000
#define NE    1600000
#define HID   128
#define DOUT  64

// Bucketing: 64 dst-nodes per bucket
#define BSH    6
#define BNODES 64
#define NBKT   782            // ceil(50000 / 64)
#define ACH    16384          // edges per scatter workgroup

// ---------------------------------------------------------------------------
// Bucket histogram: LDS hist per WG, flush with global atomics.
// ---------------------------------------------------------------------------
__global__ __launch_bounds__(256)
void bucket_hist(const int* __restrict__ dst, int* __restrict__ cnt, int n) {
    __shared__ int h[NBKT];
    for (int i = threadIdx.x; i < NBKT; i += 256) h[i] = 0;
    __syncthreads();
    for (int i = blockIdx.x * 256 + threadIdx.x; i < n; i += gridDim.x * 256)
        atomicAdd(&h[dst[i] >> BSH], 1);
    __syncthreads();
    for (int i = threadIdx.x; i < NBKT; i += 256)
        if (h[i]) atomicAdd(&cnt[i], h[i]);
}

// ---------------------------------------------------------------------------
// Exclusive scan of bucket counts (one block per graph; NBKT < 1024).
// Writes base[NBKT] = etot sentinel and initializes global cursors.
// ---------------------------------------------------------------------------
__global__ __launch_bounds__(1024)
void bucket_scan(const int* __restrict__ cnt, int* __restrict__ base,
                 int* __restrict__ gcur, int etot) {
    __shared__ int s[1024];
    const int g = blockIdx.x;
    cnt  += g * NBKT;
    base += g * (NBKT + 1);
    gcur += g * NBKT;
    int t = threadIdx.x;
    int v = (t < NBKT) ? cnt[t] : 0;
    s[t] = v;
    __syncthreads();
    for (int off = 1; off < 1024; off <<= 1) {
        int x = (t >= off) ? s[t - off] : 0;
        __syncthreads();
        s[t] += x;
        __syncthreads();
    }
    if (t < NBKT) { int b = s[t] - v; base[t] = b; gcur[t] = b; }
    if (t == NBKT) base[t] = etot;
}

// ---------------------------------------------------------------------------
// Bucketed scatter: each WG takes ACH contiguous edges, histograms them in
// LDS, reserves per-bucket ranges with ONE global atomic per non-empty
// bucket, then writes packed edges (dst_local<<16 | src) in contiguous
// per-bucket runs -> near-full-line write traffic.
// ---------------------------------------------------------------------------
__global__ __launch_bounds__(256)
void bucket_scatter(const int* __restrict__ src, const int* __restrict__ dst,
                    int* __restrict__ gcur, unsigned int* __restrict__ ebuf, int n) {
    __shared__ int hist[NBKT];
    __shared__ int lbase[NBKT];
    for (int i = threadIdx.x; i < NBKT; i += 256) hist[i] = 0;
    __syncthreads();
    const int c0 = blockIdx.x * ACH;
    const int c1 = min(c0 + ACH, n);
    for (int i = c0 + threadIdx.x; i < c1; i += 256)
        atomicAdd(&hist[dst[i] >> BSH], 1);
    __syncthreads();
    for (int i = threadIdx.x; i < NBKT; i += 256) {
        int h = hist[i];
        lbase[i] = h ? atomicAdd(&gcur[i], h) : 0;
    }
    __syncthreads();
    for (int i = threadIdx.x; i < NBKT; i += 256) hist[i] = 0;  // reuse as cursor
    __syncthreads();
    for (int i = c0 + threadIdx.x; i < c1; i += 256) {
        int d = dst[i], sv = src[i];
        int b = d >> BSH;
        int p = lbase[b] + atomicAdd(&hist[b], 1);
        ebuf[p] = ((unsigned)(d & (BNODES - 1)) << 16) | (unsigned)sv;
    }
}

// ---------------------------------------------------------------------------
// Per-bucket CSR finalize: one WG per bucket. The bucket's edges are already
// contiguous in ebuf[base[b]..base[b+1]); counting-sort them by dst_local
// (64 LDS counters) into col (src-only), which occupies exactly the same
// contiguous window -> all writes land in an ~8KB L2-resident region.
// Also emits indptr for the bucket's 64 nodes (+ sentinel at node==nnodes).
// ---------------------------------------------------------------------------
__global__ __launch_bounds__(256)
void bucket_csr(const unsigned int* __restrict__ ebuf, const int* __restrict__ base,
                int* __restrict__ indptr, int* __restrict__ col, int nnodes) {
    __shared__ int hist[BNODES];
    __shared__ int lbase[BNODES];
    __shared__ int cur[BNODES];
    const int t = threadIdx.x;
    const int b = blockIdx.x;
    const int e0 = base[b], e1 = base[b + 1];
    if (t < BNODES) { hist[t] = 0; cur[t] = 0; }
    __syncthreads();
    for (int i = e0 + t; i < e1; i += 256)
        atomicAdd(&hist[ebuf[i] >> 16], 1);
    __syncthreads();
    if (t == 0) {                       // serial 64-entry exclusive scan (cheap)
        int acc = 0;
        for (int j = 0; j < BNODES; ++j) { lbase[j] = acc; acc += hist[j]; }
    }
    __syncthreads();
    {   // indptr for this bucket's nodes (+ sentinel)
        int node = (b << BSH) + t;
        if (t < BNODES && node <= nnodes) indptr[node] = e0 + lbase[t];
        if (t == BNODES && node - 1 < nnodes && node - 1 == nnodes - 1 && b == NBKT - 1)
            ;   // (sentinel handled below for exact-multiple case)
    }
    // sentinel when nnodes is inside or at the end of this bucket
    if (t < BNODES) {
        int node = (b << BSH) + t;
        if (node == nnodes) indptr[node] = e0 + lbase[t];   // == e1 (upper locals empty)
    }
    if (b == NBKT - 1 && t == 0 && (NBKT << BSH) == nnodes) indptr[nnodes] = e1;
    for (int i = e0 + t; i < e1; i += 256) {
        unsigned pe = ebuf[i];
        int dl = pe >> 16;
        int p = e0 + lbase[dl] + atomicAdd(&cur[dl], 1);
        col[p] = (int)(pe & 0xffffu);
    }
}

// ---------------------------------------------------------------------------
// Pull-based segment mean (validated r2/3): one wave per dst node, 2 edges
// per VMEM instr. Lanes 0-31 edge i, lanes 32-63 edge i+1; float4 per lane.
// Pair-reduce via __shfl_xor(...,32).
// ---------------------------------------------------------------------------
__global__ __launch_bounds__(256)
void agg_mean(const float* __restrict__ h, const int* __restrict__ indptr,
              const int* __restrict__ col, float* __restrict__ outm, int n) {
    int w = threadIdx.x >> 6;
    int l = threadIdx.x & 63;
    int v = blockIdx.x * 4 + w;
    if (v >= n) return;
    int s = indptr[v], e = indptr[v + 1];
    const int half = l >> 5;
    const int q    = l & 31;
    const float4* h4 = (const float4*)h;
    float ax = 0.f, ay = 0.f, az = 0.f, aw = 0.f;
    int i = s;
    for (; i + 4 <= e; i += 4) {
        int u0 = col[i + half];
        int u1 = col[i + 2 + half];
        float4 x0 = h4[u0 * 32 + q];
        float4 x1 = h4[u1 * 32 + q];
        ax += x0.x + x1.x; ay += x0.y + x1.y;
        az += x0.z + x1.z; aw += x0.w + x1.w;
    }
    for (; i + 2 <= e; i += 2) {
        int u = col[i + half];
        float4 x = h4[u * 32 + q];
        ax += x.x; ay += x.y; az += x.z; aw += x.w;
    }
    if (i < e && half == 0) {
        float4 x = h4[col[i] * 32 + q];
        ax += x.x; ay += x.y; az += x.z; aw += x.w;
    }
    ax += __shfl_xor(ax, 32);
    ay += __shfl_xor(ay, 32);
    az += __shfl_xor(az, 32);
    aw += __shfl_xor(aw, 32);
    if (half == 0) {
        float inv = 1.0f / fmaxf((float)(e - s), 1.0f);
        float4 o;
        o.x = ax * inv; o.y = ay * inv; o.z = az * inv; o.w = aw * inv;
        ((float4*)outm)[v * 32 + q] = o;
    }
}

// ---------------------------------------------------------------------------
// Row-tiled fp32 GEMM: out[r][c] = act( A@W1 (+ B@W2) + bias )
// 256 threads, 64-row tile, 4 rows/thread, W staged in 64-col LDS chunks.
// Safe for out == A (block reads/writes only its own 64 rows).
// ---------------------------------------------------------------------------
#define AS 132   // Asm leading-dim stride (floats)

__device__ __forceinline__ void fma4(float4& a, float s, const float4& w) {
    a.x += s * w.x; a.y += s * w.y; a.z += s * w.z; a.w += s * w.w;
}

template <int COLS, bool TWO, bool RELU>
__global__ __launch_bounds__(256)
void gemm_rt(const float* __restrict__ A, const float* __restrict__ B,
             const float* __restrict__ W1, const float* __restrict__ W2,
             const float* __restrict__ bias, float* __restrict__ out, int nrows) {
    constexpr int NCH = COLS / 64;
    __shared__ float Asm[64 * AS];
    __shared__ float Wsm[128 * 64];
    const int t = threadIdx.x;
    const int p = t >> 4, m = t & 15, m4 = m * 4;
    const int r0 = 4 * p;
    const int rbase = blockIdx.x * 64;

    float4 acc[NCH][4];
#pragma unroll
    for (int c = 0; c < NCH; ++c)
#pragma unroll
        for (int i = 0; i < 4; ++i)
            acc[c][i] = make_float4(0.f, 0.f, 0.f, 0.f);

#pragma unroll
    for (int sidx = 0; sidx < (TWO ? 2 : 1); ++sidx) {
        const float* Asrc = (TWO && sidx) ? B : A;
        const float* Wsrc = (TWO && sidx) ? W2 : W1;
        __syncthreads();
        {   // stage 64x128 A tile as 2048 float4
            const float4* g = (const float4*)Asrc;
#pragma unroll
            for (int it = 0; it < 8; ++it) {
                int f = t + 256 * it;
                int r = f >> 5, c = f & 31;
                int gr = rbase + r;
                float4 v = make_float4(0.f, 0.f, 0.f, 0.f);
                if (gr < nrows) v = g[(size_t)gr * 32 + c];
                *(float4*)&Asm[r * AS + 4 * c] = v;
            }
        }
#pragma unroll
        for (int ch = 0; ch < NCH; ++ch) {
            if (ch > 0) __syncthreads();
            {   // stage 128x64 W chunk
                const float4* gw = (const float4*)Wsrc;
#pragma unroll
                for (int it = 0; it < 8; ++it) {
                    int f = t + 256 * it;
                    int k = f >> 4, c4 = f & 15;
                    float4 v = gw[k * (COLS / 4) + ch * 16 + c4];
                    *(float4*)&Wsm[k * 64 + 4 * c4] = v;
                }
            }
            __syncthreads();
#pragma unroll 2
            for (int k = 0; k < 128; k += 4) {
                float4 w0 = *(const float4*)&Wsm[(k + 0) * 64 + m4];
                float4 w1 = *(const float4*)&Wsm[(k + 1) * 64 + m4];
                float4 w2 = *(const float4*)&Wsm[(k + 2) * 64 + m4];
                float4 w3 = *(const float4*)&Wsm[(k + 3) * 64 + m4];
#pragma unroll
                for (int i = 0; i < 4; ++i) {
                    float4 a = *(const float4*)&Asm[(r0 + i) * AS + k];
                    fma4(acc[ch][i], a.x, w0);
                    fma4(acc[ch][i], a.y, w1);
                    fma4(acc[ch][i], a.z, w2);
                    fma4(acc[ch][i], a.w, w3);
                }
            }
        }
    }

#pragma unroll
    for (int ch = 0; ch < NCH; ++ch) {
        float4 b4 = *(const float4*)&bias[ch * 64 + m4];
#pragma unroll
        for (int i = 0; i < 4; ++i) {
            int r = rbase + r0 + i;
            if (r < nrows) {
                float4 v = acc[ch][i];
                v.x += b4.x; v.y += b4.y; v.z += b4.z; v.w += b4.w;
                if (RELU) {
                    v.x = fmaxf(v.x, 0.f); v.y = fmaxf(v.y, 0.f);
                    v.z = fmaxf(v.z, 0.f); v.w = fmaxf(v.w, 0.f);
                }
                *(float4*)&out[(size_t)r * COLS + ch * 64 + m4] = v;
            }
        }
    }
}

// ---------------------------------------------------------------------------
extern "C" void kernel_launch(void* const* d_in, const int* in_sizes, int n_in,
                              void* d_out, int out_size, void* d_ws, size_t ws_size,
                              hipStream_t stream) {
    const float* x_a   = (const float*)d_in[0];
    const float* x_b   = (const float*)d_in[1];
    const int*   ei_ab = (const int*)d_in[2];   // [2][E]: row0 src(a), row1 dst(b)
    const int*   ei_ba = (const int*)d_in[3];
    const float* Wa_in = (const float*)d_in[4];
    const float* ba_in = (const float*)d_in[5];
    const float* Wb_in = (const float*)d_in[6];
    const float* bb_in = (const float*)d_in[7];
    const float* Wl_ab = (const float*)d_in[8];   // [2][128][128]
    const float* Wr_ab = (const float*)d_in[9];
    const float* bl_ab = (const float*)d_in[10];  // [2][128]
    const float* Wl_ba = (const float*)d_in[11];
    const float* Wr_ba = (const float*)d_in[12];
    const float* bl_ba = (const float*)d_in[13];
    const float* W_out = (const float*)d_in[14];  // [128][64]
    const float* b_out = (const float*)d_in[15];
    float* out = (float*)d_out;

    // ---- workspace partition (256B aligned) ----
    char* w = (char*)d_ws;
    auto alloc = [&](size_t bytes) -> void* {
        void* pp = (void*)w;
        w += (bytes + 255) & ~(size_t)255;
        return pp;
    };
    float* hA0 = (float*)alloc((size_t)N_A * HID * 4);
    float* hA1 = (float*)alloc((size_t)N_A * HID * 4);
    float* hB0 = (float*)alloc((size_t)N_B * HID * 4);
    float* hB1 = (float*)alloc((size_t)N_B * HID * 4);
    unsigned int* ebuf_ab = (unsigned int*)alloc((size_t)NE * 4);
    unsigned int* ebuf_ba = (unsigned int*)alloc((size_t)NE * 4);
    int* col_ab   = (int*)alloc((size_t)NE * 4);
    int* col_ba   = (int*)alloc((size_t)NE * 4);
    int* indptr_b = (int*)alloc((size_t)(N_B + 1) * 4);
    int* indptr_a = (int*)alloc((size_t)(N_A + 1) * 4);
    int* cnt  = (int*)alloc((size_t)2 * NBKT * 4);        // [2][NBKT]
    int* base = (int*)alloc((size_t)2 * (NBKT + 1) * 4);  // [2][NBKT+1]
    int* gcur = (int*)alloc((size_t)2 * NBKT * 4);        // [2][NBKT]

    // ---- bucketed edge build -> true CSR (no random global scatter) ----
    hipMemsetAsync(cnt, 0, (size_t)2 * NBKT * 4, stream);
    bucket_hist<<<256, 256, 0, stream>>>(ei_ab + NE, cnt, NE);
    bucket_hist<<<256, 256, 0, stream>>>(ei_ba + NE, cnt + NBKT, NE);
    bucket_scan<<<2, 1024, 0, stream>>>(cnt, base, gcur, NE);
    const int scat_blocks = (NE + ACH - 1) / ACH;
    bucket_scatter<<<scat_blocks, 256, 0, stream>>>(ei_ab, ei_ab + NE, gcur, ebuf_ab, NE);
    bucket_scatter<<<scat_blocks, 256, 0, stream>>>(ei_ba, ei_ba + NE, gcur + NBKT, ebuf_ba, NE);
    const int* base_ab = base;
    const int* base_ba = base + (NBKT + 1);
    bucket_csr<<<NBKT, 256, 0, stream>>>(ebuf_ab, base_ab, indptr_b, col_ab, N_B);
    bucket_csr<<<NBKT, 256, 0, stream>>>(ebuf_ba, base_ba, indptr_a, col_ba, N_A);

    const int gemm_blocks_a = (N_A + 63) / 64;
    const int gemm_blocks_b = (N_B + 63) / 64;
    const int agg_blocks_a  = (N_A + 3) / 4;
    const int agg_blocks_b  = (N_B + 3) / 4;

    // ---- input projections ----
    gemm_rt<128, false, true><<<gemm_blocks_a, 256, 0, stream>>>(
        x_a, nullptr, Wa_in, nullptr, ba_in, hA0, N_A);
    gemm_rt<128, false, true><<<gemm_blocks_b, 256, 0, stream>>>(
        x_b, nullptr, Wb_in, nullptr, bb_in, hB0, N_B);

    // ---- 2 hetero layers ----
    float* ha = hA0; float* ha_alt = hA1;
    float* hb = hB0; float* hb_alt = hB1;
    for (int l = 0; l < 2; ++l) {
        const float* wl_ab = Wl_ab + (size_t)l * HID * HID;
        const float* wr_ab = Wr_ab + (size_t)l * HID * HID;
        const float* bias_ab = bl_ab + (size_t)l * HID;
        const float* wl_ba = Wl_ba + (size_t)l * HID * HID;
        const float* wr_ba = Wr_ba + (size_t)l * HID * HID;
        const float* bias_ba = bl_ba + (size_t)l * HID;

        // mean_b <- mean of h_a over a->b ; mean_a <- mean of h_b over b->a
        agg_mean<<<agg_blocks_b, 256, 0, stream>>>(ha, indptr_b, col_ab, hb_alt, N_B);
        agg_mean<<<agg_blocks_a, 256, 0, stream>>>(hb, indptr_a, col_ba, ha_alt, N_A);
        // h_b' = relu(mean_b@Wl_ab + bl_ab + h_b@Wr_ab)
        gemm_rt<128, true, true><<<gemm_blocks_b, 256, 0, stream>>>(
            hb_alt, hb, wl_ab, wr_ab, bias_ab, hb_alt, N_B);
        // h_a' = relu(mean_a@Wl_ba + bl_ba + h_a@Wr_ba)
        gemm_rt<128, true, true><<<gemm_blocks_a, 256, 0, stream>>>(
            ha_alt, ha, wl_ba, wr_ba, bias_ba, ha_alt, N_A);

        float* tmp;
        tmp = ha; ha = ha_alt; ha_alt = tmp;
        tmp = hb; hb = hb_alt; hb_alt = tmp;
    }

    // ---- output projection (no relu) ----
    gemm_rt<64, false, false><<<gemm_blocks_a, 256, 0, stream>>>(
        ha, nullptr, W_out, nullptr, b_out, out, N_A);
}

// Round 9
// 994.588 us; speedup vs baseline: 6.0420x; 1.0179x over previous
//
#include <hip/hip_runtime.h>

#define N_A   50000
#define N_B   50000
#define NE    1600000
#define HID   128
#define DOUT  64

// Bucketing: 64 dst-nodes per bucket
#define BSH    6
#define BNODES 64
#define NBKT   782            // ceil(50000 / 64)
#define ACH    16384          // edges per scatter workgroup

typedef __attribute__((ext_vector_type(8))) short bf16x8;
typedef __attribute__((ext_vector_type(4))) float f32x4;

// ---------------------------------------------------------------------------
// Bucket histogram: LDS hist per WG, flush with global atomics.
// ---------------------------------------------------------------------------
__global__ __launch_bounds__(256)
void bucket_hist(const int* __restrict__ dst, int* __restrict__ cnt, int n) {
    __shared__ int h[NBKT];
    for (int i = threadIdx.x; i < NBKT; i += 256) h[i] = 0;
    __syncthreads();
    for (int i = blockIdx.x * 256 + threadIdx.x; i < n; i += gridDim.x * 256)
        atomicAdd(&h[dst[i] >> BSH], 1);
    __syncthreads();
    for (int i = threadIdx.x; i < NBKT; i += 256)
        if (h[i]) atomicAdd(&cnt[i], h[i]);
}

// ---------------------------------------------------------------------------
// Exclusive scan of bucket counts (one block per graph; NBKT < 1024).
// ---------------------------------------------------------------------------
__global__ __launch_bounds__(1024)
void bucket_scan(const int* __restrict__ cnt, int* __restrict__ base,
                 int* __restrict__ gcur, int etot) {
    __shared__ int s[1024];
    const int g = blockIdx.x;
    cnt  += g * NBKT;
    base += g * (NBKT + 1);
    gcur += g * NBKT;
    int t = threadIdx.x;
    int v = (t < NBKT) ? cnt[t] : 0;
    s[t] = v;
    __syncthreads();
    for (int off = 1; off < 1024; off <<= 1) {
        int x = (t >= off) ? s[t - off] : 0;
        __syncthreads();
        s[t] += x;
        __syncthreads();
    }
    if (t < NBKT) { int b = s[t] - v; base[t] = b; gcur[t] = b; }
    if (t == NBKT) base[t] = etot;
}

// ---------------------------------------------------------------------------
// Bucketed scatter: packed (dst_local<<16 | src) in contiguous per-bucket runs.
// ---------------------------------------------------------------------------
__global__ __launch_bounds__(256)
void bucket_scatter(const int* __restrict__ src, const int* __restrict__ dst,
                    int* __restrict__ gcur, unsigned int* __restrict__ ebuf, int n) {
    __shared__ int hist[NBKT];
    __shared__ int lbase[NBKT];
    for (int i = threadIdx.x; i < NBKT; i += 256) hist[i] = 0;
    __syncthreads();
    const int c0 = blockIdx.x * ACH;
    const int c1 = min(c0 + ACH, n);
    for (int i = c0 + threadIdx.x; i < c1; i += 256)
        atomicAdd(&hist[dst[i] >> BSH], 1);
    __syncthreads();
    for (int i = threadIdx.x; i < NBKT; i += 256) {
        int h = hist[i];
        lbase[i] = h ? atomicAdd(&gcur[i], h) : 0;
    }
    __syncthreads();
    for (int i = threadIdx.x; i < NBKT; i += 256) hist[i] = 0;  // reuse as cursor
    __syncthreads();
    for (int i = c0 + threadIdx.x; i < c1; i += 256) {
        int d = dst[i], sv = src[i];
        int b = d >> BSH;
        int p = lbase[b] + atomicAdd(&hist[b], 1);
        ebuf[p] = ((unsigned)(d & (BNODES - 1)) << 16) | (unsigned)sv;
    }
}

// ---------------------------------------------------------------------------
// Per-bucket CSR finalize (validated r6): counting-sort inside the bucket's
// contiguous window; emits indptr (+ sentinel).
// ---------------------------------------------------------------------------
__global__ __launch_bounds__(256)
void bucket_csr(const unsigned int* __restrict__ ebuf, const int* __restrict__ base,
                int* __restrict__ indptr, int* __restrict__ col, int nnodes) {
    __shared__ int hist[BNODES];
    __shared__ int lbase[BNODES];
    __shared__ int cur[BNODES];
    const int t = threadIdx.x;
    const int b = blockIdx.x;
    const int e0 = base[b], e1 = base[b + 1];
    if (t < BNODES) { hist[t] = 0; cur[t] = 0; }
    __syncthreads();
    for (int i = e0 + t; i < e1; i += 256)
        atomicAdd(&hist[ebuf[i] >> 16], 1);
    __syncthreads();
    if (t == 0) {
        int acc = 0;
        for (int j = 0; j < BNODES; ++j) { lbase[j] = acc; acc += hist[j]; }
    }
    __syncthreads();
    if (t < BNODES) {
        int node = (b << BSH) + t;
        if (node <= nnodes) indptr[node] = e0 + lbase[t];
    }
    if (b == NBKT - 1 && t == 0 && (NBKT << BSH) == nnodes) indptr[nnodes] = e1;
    for (int i = e0 + t; i < e1; i += 256) {
        unsigned pe = ebuf[i];
        int dl = pe >> 16;
        int p = e0 + lbase[dl] + atomicAdd(&cur[dl], 1);
        col[p] = (int)(pe & 0xffffu);
    }
}

// ---------------------------------------------------------------------------
// Pull-based segment mean: one wave per dst node; 16 edges/iter -> 8 float4
// gathers in flight per wave (MLP fix for the 46%-HBM plateau seen in r6).
// ---------------------------------------------------------------------------
__global__ __launch_bounds__(256)
void agg_mean(const float* __restrict__ h, const int* __restrict__ indptr,
              const int* __restrict__ col, float* __restrict__ outm, int n) {
    int w = threadIdx.x >> 6;
    int l = threadIdx.x & 63;
    int v = blockIdx.x * 4 + w;
    if (v >= n) return;
    int s = indptr[v], e = indptr[v + 1];
    const int half = l >> 5;
    const int q    = l & 31;
    const float4* h4 = (const float4*)h;
    float ax = 0.f, ay = 0.f, az = 0.f, aw = 0.f;
    int i = s;
    for (; i + 16 <= e; i += 16) {
        int u0 = col[i +  0 + half], u1 = col[i +  2 + half];
        int u2 = col[i +  4 + half], u3 = col[i +  6 + half];
        int u4 = col[i +  8 + half], u5 = col[i + 10 + half];
        int u6 = col[i + 12 + half], u7 = col[i + 14 + half];
        float4 x0 = h4[u0 * 32 + q], x1 = h4[u1 * 32 + q];
        float4 x2 = h4[u2 * 32 + q], x3 = h4[u3 * 32 + q];
        float4 x4 = h4[u4 * 32 + q], x5 = h4[u5 * 32 + q];
        float4 x6 = h4[u6 * 32 + q], x7 = h4[u7 * 32 + q];
        ax += (x0.x + x1.x) + (x2.x + x3.x) + (x4.x + x5.x) + (x6.x + x7.x);
        ay += (x0.y + x1.y) + (x2.y + x3.y) + (x4.y + x5.y) + (x6.y + x7.y);
        az += (x0.z + x1.z) + (x2.z + x3.z) + (x4.z + x5.z) + (x6.z + x7.z);
        aw += (x0.w + x1.w) + (x2.w + x3.w) + (x4.w + x5.w) + (x6.w + x7.w);
    }
    for (; i + 4 <= e; i += 4) {
        int u0 = col[i + half], u1 = col[i + 2 + half];
        float4 x0 = h4[u0 * 32 + q], x1 = h4[u1 * 32 + q];
        ax += x0.x + x1.x; ay += x0.y + x1.y;
        az += x0.z + x1.z; aw += x0.w + x1.w;
    }
    for (; i + 2 <= e; i += 2) {
        int u = col[i + half];
        float4 x = h4[u * 32 + q];
        ax += x.x; ay += x.y; az += x.z; aw += x.w;
    }
    if (i < e && half == 0) {
        float4 x = h4[col[i] * 32 + q];
        ax += x.x; ay += x.y; az += x.z; aw += x.w;
    }
    ax += __shfl_xor(ax, 32);
    ay += __shfl_xor(ay, 32);
    az += __shfl_xor(az, 32);
    aw += __shfl_xor(aw, 32);
    if (half == 0) {
        float inv = 1.0f / fmaxf((float)(e - s), 1.0f);
        float4 o;
        o.x = ax * inv; o.y = ay * inv; o.z = az * inv; o.w = aw * inv;
        ((float4*)outm)[v * 32 + q] = o;
    }
}

// ---------------------------------------------------------------------------
// Weight prep: split each fp32 W[k][n] into bf16 hi/lo and store TRANSPOSED
// (Wt[n][k]) so MFMA B-fragments are contiguous 16B loads.
// ---------------------------------------------------------------------------
struct W11 { const float* s[11]; short* dh[11]; short* dl[11]; };

__global__ __launch_bounds__(256)
void prep_w(W11 P) {
    int m = blockIdx.y;
    int ncols = (m == 10) ? DOUT : HID;
    int e = blockIdx.x * 256 + threadIdx.x;
    if (e >= HID * ncols) return;
    int k = e / ncols, n = e - k * ncols;
    float x = P.s[m][e];
    unsigned u = __float_as_uint(x);
    unsigned hb = (u + 0x8000u) & 0xffff0000u;     // bf16 round of x
    float fl = x - __uint_as_float(hb);            // exact residual
    P.dh[m][n * HID + k] = (short)(hb >> 16);
    P.dl[m][n * HID + k] = (short)((__float_as_uint(fl) + 0x8000u) >> 16);
}

// ---------------------------------------------------------------------------
// Split-bf16 MFMA GEMM (3-term Markidis: ah*bh + ah*bl + al*bh ~ fp32).
// out[r][c] = act( A@W1 (+ B2@W2) + bias ).  No LDS: A-frags straight from
// global fp32 (split in-reg), B-frags from prepped bf16 W^T (L2-resident).
// Block = 256 thr = 4 waves; block tile 32 rows x COLS; wave w -> cols 32w.
// mfma_f32_16x16x32_bf16: A row=l&15,k=8*(l>>4)+j; B col=l&15 same k;
// D col=l&15,row=4*(l>>4)+r  [cdna4_isa §10 / learn_hip m89].
// In-place (out==A) for TWO: barrier before epilogue; blocks own their rows.
// ---------------------------------------------------------------------------
__device__ __forceinline__ void split8(const float4& a0, const float4& a1,
                                       bf16x8& hi, bf16x8& lo) {
    float xs[8] = {a0.x, a0.y, a0.z, a0.w, a1.x, a1.y, a1.z, a1.w};
#pragma unroll
    for (int j = 0; j < 8; ++j) {
        unsigned u = __float_as_uint(xs[j]);
        unsigned hb = (u + 0x8000u) & 0xffff0000u;
        float fl = xs[j] - __uint_as_float(hb);
        hi[j] = (short)(hb >> 16);
        lo[j] = (short)((__float_as_uint(fl) + 0x8000u) >> 16);
    }
}

template <int COLS, bool TWO, bool RELU>
__global__ __launch_bounds__(256)
void gemm_mfma(const float* __restrict__ A, const float* __restrict__ B2,
               const short* __restrict__ WtH1, const short* __restrict__ WtL1,
               const short* __restrict__ WtH2, const short* __restrict__ WtL2,
               const float* __restrict__ bias, float* __restrict__ out, int nrows) {
    const int wv = threadIdx.x >> 6;
    if (!TWO && wv * 32 >= COLS) return;   // idle waves only in non-barrier path
    const int l = threadIdx.x & 63;
    const int l16 = l & 15, l4 = l >> 4;
    const int rbase = blockIdx.x * 32;
    const int colbase = wv * 32;

    f32x4 acc[2][2] = {};   // [rf][cf]

#pragma unroll
    for (int sidx = 0; sidx < (TWO ? 2 : 1); ++sidx) {
        const float* Asrc = (TWO && sidx) ? B2 : A;
        const short* WH = (TWO && sidx) ? WtH2 : WtH1;
        const short* WL = (TWO && sidx) ? WtL2 : WtL1;
#pragma unroll
        for (int kb = 0; kb < 4; ++kb) {
            const int k0 = kb * 32 + l4 * 8;
            bf16x8 bh[2], bl[2];
#pragma unroll
            for (int cf = 0; cf < 2; ++cf) {
                int n = colbase + 16 * cf + l16;
                bh[cf] = *(const bf16x8*)&WH[n * HID + k0];
                bl[cf] = *(const bf16x8*)&WL[n * HID + k0];
            }
#pragma unroll
            for (int rf = 0; rf < 2; ++rf) {
                int r = rbase + 16 * rf + l16;
                float4 a0 = make_float4(0.f, 0.f, 0.f, 0.f);
                float4 a1 = make_float4(0.f, 0.f, 0.f, 0.f);
                if (r < nrows) {
                    a0 = *(const float4*)&Asrc[(size_t)r * HID + k0];
                    a1 = *(const float4*)&Asrc[(size_t)r * HID + k0 + 4];
                }
                bf16x8 ah, al;
                split8(a0, a1, ah, al);
#pragma unroll
                for (int cf = 0; cf < 2; ++cf) {
                    acc[rf][cf] = __builtin_amdgcn_mfma_f32_16x16x32_bf16(ah, bh[cf], acc[rf][cf], 0, 0, 0);
                    acc[rf][cf] = __builtin_amdgcn_mfma_f32_16x16x32_bf16(ah, bl[cf], acc[rf][cf], 0, 0, 0);
                    acc[rf][cf] = __builtin_amdgcn_mfma_f32_16x16x32_bf16(al, bh[cf], acc[rf][cf], 0, 0, 0);
                }
            }
        }
    }

    if (TWO) __syncthreads();   // close in-place read/write race across waves

#pragma unroll
    for (int rf = 0; rf < 2; ++rf)
#pragma unroll
        for (int cf = 0; cf < 2; ++cf) {
            int colg = colbase + 16 * cf + l16;
            float bi = bias[colg];
#pragma unroll
            for (int r = 0; r < 4; ++r) {
                int rowg = rbase + 16 * rf + l4 * 4 + r;
                if (rowg < nrows) {
                    float vv = acc[rf][cf][r] + bi;
                    if (RELU) vv = fmaxf(vv, 0.f);
                    out[(size_t)rowg * COLS + colg] = vv;
                }
            }
        }
}

// ---------------------------------------------------------------------------
extern "C" void kernel_launch(void* const* d_in, const int* in_sizes, int n_in,
                              void* d_out, int out_size, void* d_ws, size_t ws_size,
                              hipStream_t stream) {
    const float* x_a   = (const float*)d_in[0];
    const float* x_b   = (const float*)d_in[1];
    const int*   ei_ab = (const int*)d_in[2];   // [2][E]: row0 src(a), row1 dst(b)
    const int*   ei_ba = (const int*)d_in[3];
    const float* Wa_in = (const float*)d_in[4];
    const float* ba_in = (const float*)d_in[5];
    const float* Wb_in = (const float*)d_in[6];
    const float* bb_in = (const float*)d_in[7];
    const float* Wl_ab = (const float*)d_in[8];   // [2][128][128]
    const float* Wr_ab = (const float*)d_in[9];
    const float* bl_ab = (const float*)d_in[10];  // [2][128]
    const float* Wl_ba = (const float*)d_in[11];
    const float* Wr_ba = (const float*)d_in[12];
    const float* bl_ba = (const float*)d_in[13];
    const float* W_out = (const float*)d_in[14];  // [128][64]
    const float* b_out = (const float*)d_in[15];
    float* out = (float*)d_out;

    // ---- workspace partition (256B aligned) ----
    char* w = (char*)d_ws;
    auto alloc = [&](size_t bytes) -> void* {
        void* pp = (void*)w;
        w += (bytes + 255) & ~(size_t)255;
        return pp;
    };
    float* hA0 = (float*)alloc((size_t)N_A * HID * 4);
    float* hA1 = (float*)alloc((size_t)N_A * HID * 4);
    float* hB0 = (float*)alloc((size_t)N_B * HID * 4);
    float* hB1 = (float*)alloc((size_t)N_B * HID * 4);
    unsigned int* ebuf_ab = (unsigned int*)alloc((size_t)NE * 4);
    unsigned int* ebuf_ba = (unsigned int*)alloc((size_t)NE * 4);
    int* col_ab   = (int*)alloc((size_t)NE * 4);
    int* col_ba   = (int*)alloc((size_t)NE * 4);
    int* indptr_b = (int*)alloc((size_t)(N_B + 1) * 4);
    int* indptr_a = (int*)alloc((size_t)(N_A + 1) * 4);
    int* cnt  = (int*)alloc((size_t)2 * NBKT * 4);
    int* base = (int*)alloc((size_t)2 * (NBKT + 1) * 4);
    int* gcur = (int*)alloc((size_t)2 * NBKT * 4);
    // split-bf16 transposed weights: 10 x 128x128 + 1 x 128x64
    short* WtH = (short*)alloc((size_t)(10 * HID * HID + HID * DOUT) * 2);
    short* WtL = (short*)alloc((size_t)(10 * HID * HID + HID * DOUT) * 2);
    auto wh = [&](int i) { return WtH + (size_t)i * HID * HID; };
    auto wl = [&](int i) { return WtL + (size_t)i * HID * HID; };

    // ---- weight prep (independent of everything else) ----
    {
        W11 P;
        const float* srcs[11] = {
            Wa_in, Wb_in,
            Wl_ab, Wl_ab + HID * HID,
            Wr_ab, Wr_ab + HID * HID,
            Wl_ba, Wl_ba + HID * HID,
            Wr_ba, Wr_ba + HID * HID,
            W_out };
        for (int i = 0; i < 11; ++i) { P.s[i] = srcs[i]; P.dh[i] = wh(i); P.dl[i] = wl(i); }
        prep_w<<<dim3(64, 11), 256, 0, stream>>>(P);
    }

    // ---- bucketed edge build -> CSR ----
    hipMemsetAsync(cnt, 0, (size_t)2 * NBKT * 4, stream);
    bucket_hist<<<256, 256, 0, stream>>>(ei_ab + NE, cnt, NE);
    bucket_hist<<<256, 256, 0, stream>>>(ei_ba + NE, cnt + NBKT, NE);
    bucket_scan<<<2, 1024, 0, stream>>>(cnt, base, gcur, NE);
    const int scat_blocks = (NE + ACH - 1) / ACH;
    bucket_scatter<<<scat_blocks, 256, 0, stream>>>(ei_ab, ei_ab + NE, gcur, ebuf_ab, NE);
    bucket_scatter<<<scat_blocks, 256, 0, stream>>>(ei_ba, ei_ba + NE, gcur + NBKT, ebuf_ba, NE);
    const int* base_ab = base;
    const int* base_ba = base + (NBKT + 1);
    bucket_csr<<<NBKT, 256, 0, stream>>>(ebuf_ab, base_ab, indptr_b, col_ab, N_B);
    bucket_csr<<<NBKT, 256, 0, stream>>>(ebuf_ba, base_ba, indptr_a, col_ba, N_A);

    const int gemm_blocks = (N_A + 31) / 32;      // N_A == N_B
    const int agg_blocks  = (N_A + 3) / 4;

    // ---- input projections ----
    gemm_mfma<128, false, true><<<gemm_blocks, 256, 0, stream>>>(
        x_a, nullptr, wh(0), wl(0), nullptr, nullptr, ba_in, hA0, N_A);
    gemm_mfma<128, false, true><<<gemm_blocks, 256, 0, stream>>>(
        x_b, nullptr, wh(1), wl(1), nullptr, nullptr, bb_in, hB0, N_B);

    // ---- 2 hetero layers ----
    float* ha = hA0; float* ha_alt = hA1;
    float* hb = hB0; float* hb_alt = hB1;
    for (int l = 0; l < 2; ++l) {
        const float* bias_ab = bl_ab + (size_t)l * HID;
        const float* bias_ba = bl_ba + (size_t)l * HID;

        agg_mean<<<agg_blocks, 256, 0, stream>>>(ha, indptr_b, col_ab, hb_alt, N_B);
        agg_mean<<<agg_blocks, 256, 0, stream>>>(hb, indptr_a, col_ba, ha_alt, N_A);
        // h_b' = relu(mean_b@Wl_ab + bl_ab + h_b@Wr_ab)
        gemm_mfma<128, true, true><<<gemm_blocks, 256, 0, stream>>>(
            hb_alt, hb, wh(2 + l), wl(2 + l), wh(4 + l), wl(4 + l), bias_ab, hb_alt, N_B);
        // h_a' = relu(mean_a@Wl_ba + bl_ba + h_a@Wr_ba)
        gemm_mfma<128, true, true><<<gemm_blocks, 256, 0, stream>>>(
            ha_alt, ha, wh(6 + l), wl(6 + l), wh(8 + l), wl(8 + l), bias_ba, ha_alt, N_A);

        float* tmp;
        tmp = ha; ha = ha_alt; ha_alt = tmp;
        tmp = hb; hb = hb_alt; hb_alt = tmp;
    }

    // ---- output projection (no relu) ----
    gemm_mfma<64, false, false><<<gemm_blocks, 256, 0, stream>>>(
        ha, nullptr, wh(10), wl(10), nullptr, nullptr, b_out, out, N_A);
}